// Round 4
// baseline (386.072 us; speedup 1.0000x reference)
//
#include <hip/hip_runtime.h>
#include <hip/hip_bf16.h>

#define NROWS   32768     // 32*32*32
#define DIMD    256
#define NATOMS  1024

typedef short  bf16x8 __attribute__((ext_vector_type(8)));
typedef float  f32x4  __attribute__((ext_vector_type(4)));

__device__ __forceinline__ unsigned short bf16rne(float f) {
    unsigned u = __float_as_uint(f);
    u = u + 0x7FFFu + ((u >> 16) & 1u);
    return (unsigned short)(u >> 16);
}
__device__ __forceinline__ float bf16tof(unsigned short h) {
    return __uint_as_float(((unsigned)h) << 16);
}

// ---------------------------------------------------------------------------
// B prep: 4 planes [1024][256] bf16: 0=rep.b0, 1=rep.b1, 2=dict.b0, 3=dict.b1
// (b0 = bf16(x), b1 = bf16(x - b0)). Also dict row norms.
__global__ __launch_bounds__(256) void vq_bprep(
    const float* __restrict__ rep_w, const float* __restrict__ dict_w,
    unsigned short* __restrict__ Bs, float* __restrict__ dnorm)
{
    const int tid = threadIdx.x;
    const int atom = blockIdx.x * 32 + (tid >> 3);   // 32 blocks
    const int c8 = tid & 7;                          // 8 chunks of 32 floats
    float ss = 0.f;
#pragma unroll
    for (int m = 0; m < 2; ++m) {                    // 0=rep, 1=dict
        const float* src = (m ? dict_w : rep_w) + (size_t)atom * DIMD + c8 * 32;
        unsigned short* p0 = Bs + (size_t)(2 * m)     * 262144 + (size_t)atom * DIMD + c8 * 32;
        unsigned short* p1 = Bs + (size_t)(2 * m + 1) * 262144 + (size_t)atom * DIMD + c8 * 32;
#pragma unroll
        for (int q = 0; q < 8; ++q) {
            float4 v = *(const float4*)&src[q * 4];
            float fv[4] = {v.x, v.y, v.z, v.w};
            unsigned short a0[4], a1[4];
#pragma unroll
            for (int e = 0; e < 4; ++e) {
                float f = fv[e];
                if (m) ss = fmaf(f, f, ss);
                unsigned short b0 = bf16rne(f);
                float r1 = f - bf16tof(b0);
                a0[e] = b0;
                a1[e] = bf16rne(r1);
            }
            *(ushort4*)&p0[q * 4] = make_ushort4(a0[0], a0[1], a0[2], a0[3]);
            *(ushort4*)&p1[q * 4] = make_ushort4(a1[0], a1[1], a1[2], a1[3]);
        }
    }
    ss += __shfl_down(ss, 4, 8);
    ss += __shfl_down(ss, 2, 8);
    ss += __shfl_down(ss, 1, 8);
    if (c8 == 0) dnorm[atom] = ss;
}

// ---------------------------------------------------------------------------
// top-8 insert into sorted (ascending) register array. key = sortable(dist)<<32 | idx
__device__ __forceinline__ void top8_insert(unsigned long long ck, float cl,
                                            unsigned long long (&key)[8], float (&lg)[8]) {
    bool b[8];
#pragma unroll
    for (int j = 0; j < 8; ++j) b[j] = ck < key[j];
#pragma unroll
    for (int j = 7; j >= 1; --j) {
        unsigned long long t = b[j - 1] ? key[j - 1] : ck;
        float tl = b[j - 1] ? lg[j - 1] : cl;
        key[j] = b[j] ? t : key[j];
        lg[j]  = b[j] ? tl : lg[j];
    }
    key[0] = b[0] ? ck : key[0];
    lg[0]  = b[0] ? cl : lg[0];
}

// ---------------------------------------------------------------------------
// Main: dual GEMM via 3-term cross split (K'=768) on MFMA, A-in-registers,
// 4 row-frags/wave for B reuse. Block = 128 rows x 1024 atoms, 4 waves:
// wave w: GEMM g=w>>1 (0=logits,1=dists), row-half h=w&1 (64 rows).
// Grid = 256 blocks (1/CU). Per iter: 32 atoms; B staged via swizzled
// global_load_lds (plane per wave); online softmax-sum + top-8 scan fused.
__global__ __launch_bounds__(256, 1) void vq_main(
    const float* __restrict__ z_e, const unsigned short* __restrict__ Bs,
    const float* __restrict__ rep_b, const float* __restrict__ dnorm,
    int* __restrict__ idx_out, float* __restrict__ w_out, int* __restrict__ counts)
{
    __shared__ __align__(16) char smem[107520];
    // [0,65536): B tiles, 4 planes x 32 atom-rows x 512 B (XOR-swizzled kbyte)
    auto Ll = reinterpret_cast<float (*)[33]>(smem + 65536);   // [128][33] logits
    auto Ld = reinterpret_cast<float (*)[33]>(smem + 82432);   // [128][33] dict dots
    float* repbS  = reinterpret_cast<float*>(smem + 99328);    // [1024]
    float* dnormS = reinterpret_cast<float*>(smem + 103424);   // [1024]
    // merge overlay (over B region, barrier-separated):
    unsigned long long* mk = reinterpret_cast<unsigned long long*>(smem);  // [128][2][8]
    float* ml   = reinterpret_cast<float*>(smem + 16384);                  // [128][2][8]
    float* msum = reinterpret_cast<float*>(smem + 24576);                  // [128][2]

    const int tid = threadIdx.x;
    const int lane = tid & 63, w = tid >> 6;
    const int g = w >> 1, h = w & 1;
    const int row0 = blockIdx.x * 128;
    const int bb = row0 >> 10, hw0 = row0 & 1023;

    // ---- staging: wave w stages plane w, atoms [it*32, +32) -> 16 KB region
    // LDS linear (base + lane*16); source pre-inverse-swizzled (rule #21)
    auto stage = [&](int it) {
        const char* pb = (const char*)Bs + (size_t)w * 524288 + (size_t)it * 16384;
#pragma unroll
        for (int cc = 0; cc < 16; ++cc) {
            const int row = 2 * cc + (lane >> 5);
            const int x = (lane & 31) * 16;
            const char* gp = pb + row * 512 + (x ^ ((row & 7) << 4));
            char* lp = smem + w * 16384 + cc * 1024;   // wave-uniform; HW adds lane*16
            __builtin_amdgcn_global_load_lds(
                (const __attribute__((address_space(1))) unsigned int*)gp,
                (__attribute__((address_space(3))) unsigned int*)lp, 16, 0, 0);
        }
    };
    stage(0);

    // bias / norm tables to LDS
    for (int i = tid; i < 1024; i += 256) { repbS[i] = rep_b[i]; dnormS[i] = dnorm[i]; }

    // ---- A: wave's 64 rows x 256 k, split into a0/a1 bf16 frags (256 VGPR)
    bf16x8 A0[4][8], A1[4][8];
    {
        const float* zb = z_e + (size_t)bb * (DIMD * 1024) + (hw0 + h * 64 + (lane & 15));
#pragma unroll
        for (int rf = 0; rf < 4; ++rf)
#pragma unroll
            for (int kc = 0; kc < 8; ++kc) {
                const float* p = zb + rf * 16 + (size_t)(kc * 32 + (lane >> 4) * 8) * 1024;
                float f[8];
#pragma unroll
                for (int j = 0; j < 8; ++j) f[j] = p[(size_t)j * 1024];
#pragma unroll
                for (int j = 0; j < 8; ++j) {
                    unsigned short b0 = bf16rne(f[j]);
                    float r1 = f[j] - bf16tof(b0);
                    A0[rf][kc][j] = (short)b0;
                    A1[rf][kc][j] = (short)bf16rne(r1);
                }
            }
    }

    // scan state: thread = (row sr of 128, part sp of 2); part scans 16 atoms/iter
    const int sr = tid & 127, sp = tid >> 7;
    unsigned long long key[8];
    float lg[8];
    float sume = 0.f;
#pragma unroll
    for (int j = 0; j < 8; ++j) { key[j] = ~0ull; lg[j] = 0.f; }

    for (int it = 0; it < 32; ++it) {
        __syncthreads();   // B(it) staged (barrier drains vmcnt); Ll/Ld free

        f32x4 acc[4][2];
#pragma unroll
        for (int rf = 0; rf < 4; ++rf)
#pragma unroll
            for (int cf = 0; cf < 2; ++cf)
                acc[rf][cf] = (f32x4){0.f, 0.f, 0.f, 0.f};

        // virtual K' chunks: 0-7 a0*b0, 8-15 a0*b1, 16-23 a1*b0
#pragma unroll
        for (int vc = 0; vc < 24; ++vc) {
            const int sa = vc >> 4, pl = (vc >> 3) & 1, kc = vc & 7;
#pragma unroll
            for (int cf = 0; cf < 2; ++cf) {
                const int r = cf * 16 + (lane & 15);
                const int kb = kc * 64 + (lane >> 4) * 16;
                bf16x8 b = *(const bf16x8*)(smem + (2 * g + pl) * 16384
                                            + r * 512 + (kb ^ ((r & 7) << 4)));
#pragma unroll
                for (int rf = 0; rf < 4; ++rf) {
                    bf16x8 af = sa ? A1[rf][kc] : A0[rf][kc];
                    acc[rf][cf] = __builtin_amdgcn_mfma_f32_16x16x32_bf16(af, b, acc[rf][cf], 0, 0, 0);
                }
            }
        }

        // extract: C frag (16x16): row=(lane>>4)*4+q, col=lane&15
        {
            auto Obuf = (g == 0) ? Ll : Ld;
#pragma unroll
            for (int rf = 0; rf < 4; ++rf)
#pragma unroll
                for (int cf = 0; cf < 2; ++cf)
#pragma unroll
                    for (int q = 0; q < 4; ++q)
                        Obuf[h * 64 + rf * 16 + (lane >> 4) * 4 + q][cf * 16 + (lane & 15)]
                            = acc[rf][cf][q];
        }
        __syncthreads();   // extracts visible; B(it) reads done

        if (it < 31) stage(it + 1);   // overlaps with scan

        // online scan: 2 parts x 16 atoms per row
        const int ab = it * 32 + sp * 16;
#pragma unroll
        for (int t = 0; t < 16; ++t) {
            const int ga = ab + t;
            const int al = sp * 16 + t;
            float l = Ll[sr][al] + repbS[ga];
            float v = dnormS[ga] - 2.0f * Ld[sr][al];
            sume += expf(l);
            unsigned u = __float_as_uint(v);
            u ^= ((unsigned)((int)u >> 31) | 0x80000000u);
            unsigned long long ck = ((unsigned long long)u << 32) | (unsigned)ga;
            if (ck < key[7]) top8_insert(ck, l, key, lg);
        }
    }

    // merge the 2 partial top-8s per row, finish softmax, emit idx/w/counts
    __syncthreads();
    {
        const int o = (sr * 2 + sp) * 8;
#pragma unroll
        for (int j = 0; j < 8; ++j) { mk[o + j] = key[j]; ml[o + j] = lg[j]; }
        msum[sr * 2 + sp] = sume;
    }
    __syncthreads();
    if (tid < 128) {
        const int r = tid;
        unsigned long long K[8];
        float L[8];
#pragma unroll
        for (int j = 0; j < 8; ++j) { K[j] = mk[(r * 2) * 8 + j]; L[j] = ml[(r * 2) * 8 + j]; }
        for (int t = 0; t < 8; ++t) {
            unsigned long long ck = mk[(r * 2 + 1) * 8 + t];
            float cl = ml[(r * 2 + 1) * 8 + t];
            if (ck < K[7]) top8_insert(ck, cl, K, L);
        }
        const float s = msum[r * 2] + msum[r * 2 + 1];
        const float inv = 0.125f / s;   // softmax / SPARSITY
        const int row = row0 + r;
#pragma unroll
        for (int j = 0; j < 8; ++j) {
            const int gidx = (int)(K[j] & 0xffffffffull);
            const float wv = expf(L[j]) * inv;
            idx_out[row * 8 + j] = gidx;
            w_out[row * 8 + j] = wv;
            atomicAdd(&counts[gidx], 1);
        }
    }
}

// ---------------------------------------------------------------------------
// rep_sparse: zero-fill + scatter (runs after vq_main; also wipes Bs scratch)
__global__ __launch_bounds__(256) void vq_fill(
    const int* __restrict__ idx_in, const float* __restrict__ w_in,
    float* __restrict__ rep_sparse)
{
    const int tid = threadIdx.x;
    const int row0 = blockIdx.x * 64;
    float4 z4 = {0.f, 0.f, 0.f, 0.f};
    float4* rp4 = (float4*)rep_sparse + (size_t)row0 * (NATOMS / 4) + tid;
    for (int r = 0; r < 64; ++r)
        rp4[(size_t)r * (NATOMS / 4)] = z4;
    __syncthreads();
    if (tid < 64) {
        const int row = row0 + tid;
#pragma unroll
        for (int j = 0; j < 8; ++j)
            rep_sparse[(size_t)row * NATOMS + idx_in[row * 8 + j]] = w_in[row * 8 + j];
    }
}

// ---------------------------------------------------------------------------
// Reconstruct z_dl, write z_st (NCHW), accumulate squared-error partials.
__global__ __launch_bounds__(256, 2) void vq_recon(
    const float* __restrict__ z_e, const float* __restrict__ dict_w,
    const int* __restrict__ idx_in, const float* __restrict__ w_in,
    float* __restrict__ z_st, float* __restrict__ partials)
{
    __shared__ float zdl[32][257];
    __shared__ float red[256];
    const int tid = threadIdx.x;
    const int row0 = blockIdx.x * 32;

    for (int r = 0; r < 32; ++r) {
        const int row = row0 + r;
        float acc = 0.f;
#pragma unroll
        for (int j = 0; j < 8; ++j) {
            const int ix = idx_in[row * 8 + j];
            const float wv = w_in[row * 8 + j];
            acc = fmaf(wv, dict_w[(size_t)ix * DIMD + tid], acc);
        }
        zdl[r][tid] = acc;
    }
    __syncthreads();

    const int bb = row0 >> 10, hw0 = row0 & 1023;
    const float* zb = z_e + (size_t)bb * (DIMD * 1024) + hw0;
    float* ob = z_st + (size_t)bb * (DIMD * 1024) + hw0;
    const int m = tid & 31, dg = tid >> 5;
    float sacc = 0.f;
    for (int itr = 0; itr < 32; ++itr) {
        const int d = itr * 8 + dg;
        const float ze = zb[(size_t)d * 1024 + m];
        const float zd = zdl[m][d];
        const float diff = zd - ze;
        ob[(size_t)d * 1024 + m] = ze + diff;
        sacc = fmaf(diff, diff, sacc);
    }
    red[tid] = sacc;
    __syncthreads();
    for (int s = 128; s > 0; s >>= 1) {
        if (tid < s) red[tid] += red[tid + s];
        __syncthreads();
    }
    if (tid == 0) partials[blockIdx.x] = red[0];
}

// ---------------------------------------------------------------------------
// Finalize: loss and perplexity
__global__ void vq_final(const float* __restrict__ partials,
                         const int* __restrict__ counts,
                         float* __restrict__ out_loss, float* __restrict__ out_perp)
{
    __shared__ double dred[256];
    __shared__ float fred[256];
    const int tid = threadIdx.x;
    double s = 0.0;
    for (int i = tid; i < 1024; i += 256) s += (double)partials[i];
    dred[tid] = s;
    __syncthreads();
    for (int st = 128; st > 0; st >>= 1) {
        if (tid < st) dred[tid] += dred[tid + st];
        __syncthreads();
    }
    float ps = 0.f;
    for (int i = tid; i < NATOMS; i += 256) {
        const float p = (float)counts[i] * (1.0f / 262144.0f);
        ps += p * logf(p + 1e-10f);
    }
    fred[tid] = ps;
    __syncthreads();
    for (int st = 128; st > 0; st >>= 1) {
        if (tid < st) fred[tid] += fred[tid + st];
        __syncthreads();
    }
    if (tid == 0) {
        *out_loss = 0.25f * (float)(dred[0] / 8388608.0);
        *out_perp = expf(-fred[0]);
    }
}

// ---------------------------------------------------------------------------
extern "C" void kernel_launch(void* const* d_in, const int* in_sizes, int n_in,
                              void* d_out, int out_size, void* d_ws, size_t ws_size,
                              hipStream_t stream) {
    const float* z_e    = (const float*)d_in[0];
    const float* dict_w = (const float*)d_in[1];
    const float* rep_w  = (const float*)d_in[2];
    const float* rep_b  = (const float*)d_in[3];

    float* out = (float*)d_out;
    float* out_loss   = out;                      // [0]
    float* z_st       = out + 1;                  // [1 .. 8388608]
    float* out_perp   = out + 1 + 8388608;        // [8388609]
    float* rep_sparse = out + 2 + 8388608;        // [8388610 ..] 32768x1024

    // Bs scratch (4 MB, 4 planes) carved from rep_sparse region, 16B-aligned;
    // vq_fill rewrites the whole region afterwards.
    unsigned short* Bs = (unsigned short*)(((uintptr_t)rep_sparse + 15) & ~(uintptr_t)15);

    char* ws = (char*)d_ws;
    int*   idx_out  = (int*)ws;                             // 1 MB
    float* w_out    = (float*)(ws + (1 << 20));             // 1 MB
    int*   counts   = (int*)(ws + (2 << 20));               // 4 KB
    float* dnorm    = (float*)(ws + (2 << 20) + 4096);      // 4 KB
    float* partials = (float*)(ws + (2 << 20) + 8192);      // 4 KB

    hipMemsetAsync(counts, 0, NATOMS * sizeof(int), stream);

    vq_bprep<<<32, 256, 0, stream>>>(rep_w, dict_w, Bs, dnorm);
    vq_main<<<NROWS / 128, 256, 0, stream>>>(z_e, Bs, rep_b, dnorm,
                                             idx_out, w_out, counts);
    vq_fill<<<NROWS / 64, 256, 0, stream>>>(idx_out, w_out, rep_sparse);
    vq_recon<<<NROWS / 32, 256, 0, stream>>>(z_e, dict_w, idx_out, w_out, z_st, partials);
    vq_final<<<1, 256, 0, stream>>>(partials, counts, out_loss, out_perp);
}

// Round 5
// 317.991 us; speedup vs baseline: 1.2141x; 1.2141x over previous
//
#include <hip/hip_runtime.h>
#include <hip/hip_bf16.h>
#include <stdint.h>

#define NROWS   32768     // 32*32*32
#define DIMD    256
#define NATOMS  1024

typedef short  bf16x8 __attribute__((ext_vector_type(8)));
typedef float  f32x4  __attribute__((ext_vector_type(4)));

__device__ __forceinline__ unsigned short bf16rne(float f) {
    unsigned u = __float_as_uint(f);
    u = u + 0x7FFFu + ((u >> 16) & 1u);
    return (unsigned short)(u >> 16);
}

// ---------------------------------------------------------------------------
// B prep: planes Bs[2][8][1024][32] bf16 (m: 0=rep,1=dict; kc; atom; k-in-32)
// K-major tiling -> each MFMA atom-fragment is a contiguous 1KB global read.
// Also dict row norms (fp32).
__global__ __launch_bounds__(256) void vq_bprep(
    const float* __restrict__ rep_w, const float* __restrict__ dict_w,
    unsigned short* __restrict__ Bs, float* __restrict__ dnorm)
{
    const int tid = threadIdx.x;
    const int atom = blockIdx.x * 32 + (tid >> 3);   // 32 blocks
    const int kc = tid & 7;                          // k-chunk of 32
    float ss = 0.f;
#pragma unroll
    for (int m = 0; m < 2; ++m) {
        const float* src = (m ? dict_w : rep_w) + (size_t)atom * DIMD + kc * 32;
        unsigned short* dst = Bs + (size_t)m * 262144 + (size_t)kc * 32768 + atom * 32;
#pragma unroll
        for (int q = 0; q < 8; ++q) {
            float4 v = *(const float4*)&src[q * 4];
            float fv[4] = {v.x, v.y, v.z, v.w};
            unsigned short a0[4];
#pragma unroll
            for (int e = 0; e < 4; ++e) {
                if (m) ss = fmaf(fv[e], fv[e], ss);
                a0[e] = bf16rne(fv[e]);
            }
            *(ushort4*)&dst[q * 4] = make_ushort4(a0[0], a0[1], a0[2], a0[3]);
        }
    }
    ss += __shfl_down(ss, 4, 8);
    ss += __shfl_down(ss, 2, 8);
    ss += __shfl_down(ss, 1, 8);
    if (kc == 0) dnorm[atom] = ss;
}

// ---------------------------------------------------------------------------
// register top-8 insert, 3 payload arrays (u32 dist-key, f32 logit, u32 idx).
// Strict < keeps incumbent on ties => lower index wins (ascending scan).
__device__ __forceinline__ void ins8(unsigned u, float l, unsigned ix,
                                     unsigned (&kd)[8], float (&lv)[8], unsigned (&iv)[8]) {
    bool b[8];
#pragma unroll
    for (int j = 0; j < 8; ++j) b[j] = u < kd[j];
#pragma unroll
    for (int j = 7; j >= 1; --j) {
        kd[j] = b[j] ? (b[j - 1] ? kd[j - 1] : u)  : kd[j];
        lv[j] = b[j] ? (b[j - 1] ? lv[j - 1] : l)  : lv[j];
        iv[j] = b[j] ? (b[j - 1] ? iv[j - 1] : ix) : iv[j];
    }
    if (b[0]) { kd[0] = u; lv[0] = l; iv[0] = ix; }
}

// u64 merge insert (key = dist<<32 | idx), payload logit
__device__ __forceinline__ void ins8m(unsigned long long ck, float cl,
                                      unsigned long long (&key)[8], float (&lg)[8]) {
    bool b[8];
#pragma unroll
    for (int j = 0; j < 8; ++j) b[j] = ck < key[j];
#pragma unroll
    for (int j = 7; j >= 1; --j) {
        key[j] = b[j] ? (b[j - 1] ? key[j - 1] : ck) : key[j];
        lg[j]  = b[j] ? (b[j - 1] ? lg[j - 1]  : cl) : lg[j];
    }
    if (b[0]) { key[0] = ck; lg[0] = cl; }
}

// ---------------------------------------------------------------------------
// Main: dual GEMM (logits+dists, 1-term bf16) with swapped MFMA operands so
// each lane owns one flat-row's online softmax-sum + top-8 entirely in
// registers. No LDS in the hot loop; B frags stream global->reg (L1/L2).
// Block = 128 rows, 4 waves (wave = 32 rows = 2 row-frags), grid 256.
// Epilogue: merge 4 lane-group partials/row, rep_sparse zero+scatter.
__global__ __launch_bounds__(256, 1) void vq_main(
    const float* __restrict__ z_e, const unsigned short* __restrict__ Bs,
    const float* __restrict__ rep_b, const float* __restrict__ dnorm,
    float* __restrict__ rep_sparse, int* __restrict__ idx_out,
    float* __restrict__ w_out, int* __restrict__ counts)
{
    __shared__ float rbS[1024];
    __shared__ float dnS[1024];
    __shared__ unsigned mkS[128 * 4 * 8];
    __shared__ float    mlS[128 * 4 * 8];
    __shared__ unsigned miS[128 * 4 * 8];
    __shared__ float    msS[128 * 4];

    const int tid = threadIdx.x;
    const int lane = tid & 63, w = tid >> 6;
    const int c = lane & 15, lg = lane >> 4;
    const int row0 = blockIdx.x * 128;
    const int bb = row0 >> 10, hw0 = row0 & 1023;

    for (int i = tid; i < 1024; i += 256) { rbS[i] = rep_b[i]; dnS[i] = dnorm[i]; }

    const char* pL = (const char*)Bs;             // rep plane  [8][1024][32]
    const char* pD = (const char*)Bs + 524288;    // dict plane

    // first B tile (atoms 0..15): frag = 16 atoms x 32k, contiguous 1KB
    bf16x8 bL[8], bD[8];
    {
        const int off = (c << 6) + (lg << 4);
#pragma unroll
        for (int kc = 0; kc < 8; ++kc) {
            bL[kc] = *(const bf16x8*)(pL + ((size_t)kc << 16) + off);
            bD[kc] = *(const bf16x8*)(pD + ((size_t)kc << 16) + off);
        }
    }

    // A: wave's 32 rows (w*32 + rf*16 + c), k = kc*32 + lg*8 + e, bf16 1-term
    bf16x8 A[2][8];
    {
        const float* zb = z_e + (size_t)bb * 262144 + hw0 + w * 32 + c;
#pragma unroll
        for (int rf = 0; rf < 2; ++rf)
#pragma unroll
            for (int kc = 0; kc < 8; ++kc) {
                float f[8];
#pragma unroll
                for (int e = 0; e < 8; ++e)
                    f[e] = zb[rf * 16 + (size_t)(kc * 32 + lg * 8 + e) * 1024];
#pragma unroll
                for (int e = 0; e < 8; ++e)
                    A[rf][kc][e] = (short)bf16rne(f[e]);
            }
    }
    __syncthreads();   // tables staged

    // per-lane online state: 2 row-frags x (top8 + softmax sum)
    unsigned kd[2][8], iv[2][8];
    float lv[2][8];
    float sume[2] = {0.f, 0.f};
#pragma unroll
    for (int rf = 0; rf < 2; ++rf)
#pragma unroll
        for (int j = 0; j < 8; ++j) { kd[rf][j] = 0xFFFFFFFFu; iv[rf][j] = 0u; lv[rf][j] = 0.f; }

    for (int it = 0; it < 64; ++it) {
        __builtin_amdgcn_s_barrier();   // align waves for L1 tile reuse (no data dep)

        f32x4 aL[2], aD[2];
#pragma unroll
        for (int rf = 0; rf < 2; ++rf) { aL[rf] = (f32x4){0,0,0,0}; aD[rf] = (f32x4){0,0,0,0}; }

        // D[atom][flatrow]: A-operand = atom frag, B-operand = flat-row frag
#pragma unroll
        for (int kc = 0; kc < 8; ++kc)
#pragma unroll
            for (int rf = 0; rf < 2; ++rf) {
                aL[rf] = __builtin_amdgcn_mfma_f32_16x16x32_bf16(bL[kc], A[rf][kc], aL[rf], 0, 0, 0);
                aD[rf] = __builtin_amdgcn_mfma_f32_16x16x32_bf16(bD[kc], A[rf][kc], aD[rf], 0, 0, 0);
            }

        // prefetch next tile (overwrites bL/bD after last MFMA read)
        if (it < 63) {
            const int off = (((it + 1) * 16 + c) << 6) + (lg << 4);
#pragma unroll
            for (int kc = 0; kc < 8; ++kc) {
                bL[kc] = *(const bf16x8*)(pL + ((size_t)kc << 16) + off);
                bD[kc] = *(const bf16x8*)(pD + ((size_t)kc << 16) + off);
            }
        }

        // in-register scan: lane's flat-row = w*32+rf*16+c; atoms lg*4+q
#pragma unroll
        for (int q = 0; q < 4; ++q) {
            const int atom = (it << 4) + (lg << 2) + q;
            const float rb = rbS[atom];
            const float dn = dnS[atom];
#pragma unroll
            for (int rf = 0; rf < 2; ++rf) {
                const float l = aL[rf][q] + rb;
                const float v = dn - 2.0f * aD[rf][q];
                sume[rf] += __expf(l);
                unsigned u = __float_as_uint(v);
                u ^= ((unsigned)((int)u >> 31) | 0x80000000u);
                if (u < kd[rf][7]) ins8(u, l, (unsigned)atom, kd[rf], lv[rf], iv[rf]);
            }
        }
    }

    // publish per-lane states: row = w*32+rf*16+c, part = lg
#pragma unroll
    for (int rf = 0; rf < 2; ++rf) {
        const int s = (w * 32 + rf * 16 + c) * 4 + lg;
#pragma unroll
        for (int j = 0; j < 8; ++j) {
            mkS[s * 8 + j] = kd[rf][j];
            mlS[s * 8 + j] = lv[rf][j];
            miS[s * 8 + j] = iv[rf][j];
        }
        msS[s] = sume[rf];
    }
    __syncthreads();

    // zero-fill this block's 128 rows of rep_sparse (replaces memset kernel)
    {
        float4 z4 = {0.f, 0.f, 0.f, 0.f};
        float4* rp4 = (float4*)rep_sparse + (size_t)row0 * (NATOMS / 4) + tid;
        for (int r = 0; r < 128; ++r)
            rp4[(size_t)r * (NATOMS / 4)] = z4;
    }
    __syncthreads();   // drains the zero stores (vmcnt(0) before barrier)

    if (tid < 128) {
        const int r = tid;
        unsigned long long K[8];
        float L[8];
#pragma unroll
        for (int j = 0; j < 8; ++j) { K[j] = ~0ull; L[j] = 0.f; }
        for (int p = 0; p < 4; ++p)
            for (int t = 0; t < 8; ++t) {
                const int s = (r * 4 + p) * 8 + t;
                unsigned long long ck = ((unsigned long long)mkS[s] << 32) | miS[s];
                if (ck < K[7]) ins8m(ck, mlS[s], K, L);
            }
        const float ssum = msS[r * 4] + msS[r * 4 + 1] + msS[r * 4 + 2] + msS[r * 4 + 3];
        const float inv = 0.125f / ssum;   // softmax / SPARSITY
        const int row = row0 + r;
#pragma unroll
        for (int j = 0; j < 8; ++j) {
            const int gidx = (int)(K[j] & 0x3ffull);
            const float wv = __expf(L[j]) * inv;
            idx_out[row * 8 + j] = gidx;
            w_out[row * 8 + j] = wv;
            rep_sparse[(size_t)row * NATOMS + gidx] = wv;
            atomicAdd(&counts[gidx], 1);
        }
    }
}

// ---------------------------------------------------------------------------
// Reconstruct z_dl, write z_st (NCHW), accumulate squared-error partials.
__global__ __launch_bounds__(256, 2) void vq_recon(
    const float* __restrict__ z_e, const float* __restrict__ dict_w,
    const int* __restrict__ idx_in, const float* __restrict__ w_in,
    float* __restrict__ z_st, float* __restrict__ partials)
{
    __shared__ float zdl[32][257];
    __shared__ float red[256];
    const int tid = threadIdx.x;
    const int row0 = blockIdx.x * 32;

    for (int r = 0; r < 32; ++r) {
        const int row = row0 + r;
        float acc = 0.f;
#pragma unroll
        for (int j = 0; j < 8; ++j) {
            const int ix = idx_in[row * 8 + j];
            const float wv = w_in[row * 8 + j];
            acc = fmaf(wv, dict_w[(size_t)ix * DIMD + tid], acc);
        }
        zdl[r][tid] = acc;
    }
    __syncthreads();

    const int bb = row0 >> 10, hw0 = row0 & 1023;
    const float* zb = z_e + (size_t)bb * (DIMD * 1024) + hw0;
    float* ob = z_st + (size_t)bb * (DIMD * 1024) + hw0;
    const int m = tid & 31, dg = tid >> 5;
    float sacc = 0.f;
    for (int itr = 0; itr < 32; ++itr) {
        const int d = itr * 8 + dg;
        const float ze = zb[(size_t)d * 1024 + m];
        const float zd = zdl[m][d];
        const float diff = zd - ze;
        ob[(size_t)d * 1024 + m] = ze + diff;   // reference rounding path
        sacc = fmaf(diff, diff, sacc);
    }
    red[tid] = sacc;
    __syncthreads();
    for (int s = 128; s > 0; s >>= 1) {
        if (tid < s) red[tid] += red[tid + s];
        __syncthreads();
    }
    if (tid == 0) partials[blockIdx.x] = red[0];
}

// ---------------------------------------------------------------------------
// Finalize: loss and perplexity (deterministic fixed-order reductions)
__global__ void vq_final(const float* __restrict__ partials,
                         const int* __restrict__ counts,
                         float* __restrict__ out_loss, float* __restrict__ out_perp)
{
    __shared__ double dred[256];
    __shared__ float fred[256];
    const int tid = threadIdx.x;
    double s = 0.0;
    for (int i = tid; i < 1024; i += 256) s += (double)partials[i];
    dred[tid] = s;
    __syncthreads();
    for (int st = 128; st > 0; st >>= 1) {
        if (tid < st) dred[tid] += dred[tid + st];
        __syncthreads();
    }
    float ps = 0.f;
    for (int i = tid; i < NATOMS; i += 256) {
        const float p = (float)counts[i] * (1.0f / 262144.0f);
        ps += p * logf(p + 1e-10f);
    }
    fred[tid] = ps;
    __syncthreads();
    for (int st = 128; st > 0; st >>= 1) {
        if (tid < st) fred[tid] += fred[tid + st];
        __syncthreads();
    }
    if (tid == 0) {
        *out_loss = 0.25f * (float)(dred[0] / 8388608.0);
        *out_perp = expf(-fred[0]);
    }
}

// ---------------------------------------------------------------------------
extern "C" void kernel_launch(void* const* d_in, const int* in_sizes, int n_in,
                              void* d_out, int out_size, void* d_ws, size_t ws_size,
                              hipStream_t stream) {
    const float* z_e    = (const float*)d_in[0];
    const float* dict_w = (const float*)d_in[1];
    const float* rep_w  = (const float*)d_in[2];
    const float* rep_b  = (const float*)d_in[3];

    float* out = (float*)d_out;
    float* out_loss   = out;                      // [0]
    float* z_st       = out + 1;                  // [1 .. 8388608]
    float* out_perp   = out + 1 + 8388608;        // [8388609]
    float* rep_sparse = out + 2 + 8388608;        // [8388610 ..] 32768x1024

    // Bs scratch (1 MB, 2 planes) parked INSIDE the z_st output region
    // (offset 16 MB). vq_recon rewrites all of z_st after vq_main finishes,
    // so no live data is clobbered and nothing leaks across calls.
    unsigned short* Bs = (unsigned short*)((((uintptr_t)(z_st + 4194304)) + 255) & ~(uintptr_t)255);

    char* ws = (char*)d_ws;
    int*   idx_out  = (int*)ws;                             // 1 MB
    float* w_out    = (float*)(ws + (1 << 20));             // 1 MB
    int*   counts   = (int*)(ws + (2 << 20));               // 4 KB
    float* dnorm    = (float*)(ws + (2 << 20) + 4096);      // 4 KB
    float* partials = (float*)(ws + (2 << 20) + 8192);      // 4 KB

    hipMemsetAsync(counts, 0, NATOMS * sizeof(int), stream);

    vq_bprep<<<32, 256, 0, stream>>>(rep_w, dict_w, Bs, dnorm);
    vq_main<<<NROWS / 128, 256, 0, stream>>>(z_e, Bs, rep_b, dnorm,
                                             rep_sparse, idx_out, w_out, counts);
    vq_recon<<<NROWS / 32, 256, 0, stream>>>(z_e, dict_w, idx_out, w_out, z_st, partials);
    vq_final<<<1, 256, 0, stream>>>(partials, counts, out_loss, out_perp);
}